// Round 7
// baseline (34.042 us; speedup 1.0000x reference)
//
#include <hip/hip_runtime.h>
#include <hip/hip_bf16.h>

// S=128, Q=8192, H=230
//   logits[s,q] = a[s] + (c[q]+b) - 2*sum_k (w*x)[s,k]*y[q,k]
// prep (128 blocks): xwb[128][256]=bf16(w*x) zero-padded, asum[s]=sum w*x^2 (f32),
//                    zeroes the arrival counter.
// main (512 blocks x 512 thr): per block one 16-q tile, all 128 s (8 waves,
//   each wave one 16x16 MFMA tile). y-tile -> swizzled bf16 LDS; c[q] from tile;
//   labels + a[s] prefetched at top; fused sigmoid+BCE; deterministic
//   last-block loss reduce (device-scope atomics, fixed order).

#define S_DIM 128
#define Q_DIM 8192
#define H_DIM 230
#define K2    256
#define SQ    (S_DIM * Q_DIM)
#define QB    16
#define NBLK  (Q_DIM / QB)     // 512

using short8 = __attribute__((ext_vector_type(8))) short;   // 8 bf16
using f32x4  = __attribute__((ext_vector_type(4))) float;

__device__ __forceinline__ float bf16_to_f32(short bits) {
    unsigned u = ((unsigned)(unsigned short)bits) << 16;
    return __uint_as_float(u);
}

// ---------------- Kernel 1: prep ----------------
__global__ __launch_bounds__(256) void prep_kernel(
    const float* __restrict__ x, const float* __restrict__ w,
    __hip_bfloat16* __restrict__ xwb, float* __restrict__ asum,
    unsigned* __restrict__ cnt)
{
    __shared__ float lred[4];
    const int tid = threadIdx.x, s = blockIdx.x;
    if (s == 0 && tid == 0) *cnt = 0u;          // reset arrival counter each call

    float xv = 0.f, wv = 0.f;
    if (tid < H_DIM) { xv = x[s * H_DIM + tid]; wv = w[tid]; }
    float wx = wv * xv;
    xwb[s * K2 + tid] = __float2bfloat16(wx);   // 0 for tid>=230

    float p = wx * xv;                          // w*x^2 (f32 exact)
    #pragma unroll
    for (int off = 32; off >= 1; off >>= 1) p += __shfl_down(p, off, 64);
    if ((tid & 63) == 0) lred[tid >> 6] = p;
    __syncthreads();
    if (tid == 0) asum[s] = lred[0] + lred[1] + lred[2] + lred[3];
}

// ---------------- Kernel 2: main ----------------
// grid=512, block=512 (8 waves). Wave wid: s in [16*wid, 16*wid+16).
__global__ __launch_bounds__(512, 4) void main_kernel(
    const float* __restrict__ y, const int* __restrict__ label,
    const __hip_bfloat16* __restrict__ xwb, const float* __restrict__ asum,
    const float* __restrict__ w, const float* __restrict__ bptr,
    float* __restrict__ out, float* __restrict__ lossws, unsigned* __restrict__ cnt)
{
    __shared__ __align__(16) short ylb[QB * K2];   // 8 KB bf16, XOR-swizzled
    __shared__ float wl[K2];
    __shared__ float cpart[32][17];
    __shared__ float cq[QB];
    __shared__ float lred[8];
    __shared__ unsigned islast;

    const int tid = threadIdx.x, bid = blockIdx.x;
    const int q0 = bid * QB;
    const int wid = tid >> 6, l = tid & 63;
    const int lm = l & 15, lh = l >> 4;
    const int s_base = wid * 16;
    const int qg = q0 + lm;
    char* ylc = reinterpret_cast<char*>(ylb);

    // ---- prefetch epilogue operands (in flight under staging + MFMA) ----
    const size_t obase = (size_t)(s_base + lh * 4) * Q_DIM + qg;
    int labs[4]; float asv[4];
    #pragma unroll
    for (int r = 0; r < 4; ++r) labs[r] = label[obase + (size_t)r * Q_DIM];
    #pragma unroll
    for (int r = 0; r < 4; ++r) asv[r] = asum[s_base + lh * 4 + r];

    // ---- w -> LDS (zero-padded) ----
    if (tid < K2) wl[tid] = (tid < H_DIM) ? w[tid] : 0.0f;

    // ---- stage y tile (16 x 230 f32 = 920 float4, contiguous, 16B-aligned) ----
    const float4* ysrc4 = reinterpret_cast<const float4*>(y + (size_t)q0 * H_DIM);
    #pragma unroll
    for (int it = 0; it < 2; ++it) {
        int i4 = tid + 512 * it;
        if (i4 < (QB * H_DIM) / 4) {
            float4 v = ysrc4[i4];
            float vv[4] = {v.x, v.y, v.z, v.w};
            #pragma unroll
            for (int j = 0; j < 4; ++j) {
                int e = i4 * 4 + j;
                int r = e / H_DIM;
                int c = e - r * H_DIM;
                int byt = ((r << 9) + (c << 1)) ^ ((r & 7) << 4);
                *reinterpret_cast<__hip_bfloat16*>(ylc + byt) = __float2bfloat16(vv[j]);
            }
        }
    }
    if (tid < QB * (K2 - H_DIM)) {   // zero-fill k = 230..255 (16*26 = 416)
        int r = tid & 15, c = H_DIM + (tid >> 4);
        int byt = ((r << 9) + (c << 1)) ^ ((r & 7) << 4);
        *reinterpret_cast<__hip_bfloat16*>(ylc + byt) = __float2bfloat16(0.0f);
    }
    __syncthreads();

    // ---- c[q]: 32 chunks of 8 k per q-row, vector LDS reads ----
    {
        const int r = tid & 15, ch = tid >> 4;     // ch in 0..31
        const int k0 = ch * 8;
        int byt = ((r << 9) + (k0 << 1)) ^ ((r & 7) << 4);
        short8 v8 = *reinterpret_cast<const short8*>(ylc + byt);
        float p = 0.f;
        #pragma unroll
        for (int j = 0; j < 8; ++j) {
            float v = bf16_to_f32(v8[j]);
            p = fmaf(wl[k0 + j] * v, v, p);
        }
        cpart[ch][r] = p;
    }
    __syncthreads();
    if (tid < QB) {
        float c = 0.f;
        #pragma unroll
        for (int ch = 0; ch < 32; ++ch) c += cpart[ch][tid];
        cq[tid] = c + bptr[0];
    }
    __syncthreads();

    // ---- MFMA: one 16x16 tile per wave, A streamed from L2-hot xwb ----
    const short* A = reinterpret_cast<const short*>(xwb) + (s_base + lm) * K2 + lh * 8;
    f32x4 acc = {0.f, 0.f, 0.f, 0.f};
    #pragma unroll
    for (int ks = 0; ks < 8; ++ks) {
        short8 a = *reinterpret_cast<const short8*>(A + ks * 32);
        int byt = ((lm << 9) + ((ks * 32 + lh * 8) << 1)) ^ ((lm & 7) << 4);
        short8 bf = *reinterpret_cast<const short8*>(ylc + byt);
        acc = __builtin_amdgcn_mfma_f32_16x16x32_bf16(a, bf, acc, 0, 0, 0);
    }

    // ---- epilogue: D row=(l>>4)*4+r (s), col=lm (q) ----
    float lsum = 0.f;
    const float cqv = cq[lm];
    #pragma unroll
    for (int r = 0; r < 4; ++r) {
        float z = asv[r] + cqv - 2.0f * acc[r];
        float sc = 1.0f / (1.0f + __expf(-z));
        out[obase + (size_t)r * Q_DIM] = sc;
        float lab = (float)labs[r];
        float bce = fmaxf(z, 0.f) - z * lab + __logf(1.0f + __expf(-fabsf(z)));
        lsum += bce;
    }
    #pragma unroll
    for (int off = 32; off >= 1; off >>= 1) lsum += __shfl_down(lsum, off, 64);
    if (l == 0) lred[wid] = lsum;
    __syncthreads();

    // ---- deterministic cross-block loss: last block reduces in fixed order ----
    if (tid == 0) {
        float blk = 0.f;
        #pragma unroll
        for (int i = 0; i < 8; ++i) blk += lred[i];
        atomicExch(&lossws[bid], blk);          // device-scope coherent store
        __threadfence();
        unsigned old = atomicAdd(cnt, 1u);
        islast = (old == NBLK - 1) ? 1u : 0u;
    }
    __syncthreads();
    if (islast) {
        __threadfence();
        float p = atomicAdd(&lossws[tid], 0.0f);   // device-scope coherent read
        #pragma unroll
        for (int off = 32; off >= 1; off >>= 1) p += __shfl_down(p, off, 64);
        __syncthreads();                            // lred reuse safe
        if (l == 0) lred[wid] = p;
        __syncthreads();
        if (tid == 0) {
            float t = 0.f;
            #pragma unroll
            for (int i = 0; i < 8; ++i) t += lred[i];
            out[SQ] = t * (1.0f / (float)SQ);
        }
    }
}

extern "C" void kernel_launch(void* const* d_in, const int* in_sizes, int n_in,
                              void* d_out, int out_size, void* d_ws, size_t ws_size,
                              hipStream_t stream) {
    const float* x = (const float*)d_in[0];     // [128,230]
    const float* y = (const float*)d_in[1];     // [8192,230]
    const int* label = (const int*)d_in[2];     // [128,8192]
    const float* w = (const float*)d_in[3];     // [230]
    const float* b = (const float*)d_in[4];     // [1]
    float* out = (float*)d_out;                 // [128*8192 + 1]

    char* ws = (char*)d_ws;
    __hip_bfloat16* xwb = (__hip_bfloat16*)ws;          // 64 KB
    float* asum   = (float*)(ws + S_DIM * K2 * 2);      // [128]
    float* lossws = asum + S_DIM;                       // [512]
    unsigned* cnt = (unsigned*)(lossws + NBLK);         // [1]

    prep_kernel<<<S_DIM, 256, 0, stream>>>(x, w, xwb, asum, cnt);
    main_kernel<<<NBLK, 512, 0, stream>>>(y, label, xwb, asum, w, b, out, lossws, cnt);
}

// Round 8
// 21.942 us; speedup vs baseline: 1.5514x; 1.5514x over previous
//
#include <hip/hip_runtime.h>
#include <hip/hip_bf16.h>

// S=128, Q=8192, H=230
//   logits[s,q] = a[s] + c[q] + b - 2*sum_k wx[s,k]*y[q,k]
//   a[s]=sum w*x^2 (f32), c[q]=sum w*y^2 (f32), dot via bf16 MFMA (f32 acc).
// r3-winner structure (23.4us) + label prefetch + vector c[q] reads.
// All reductions fixed-order (graph replay must be bitwise identical).

#define S_DIM 128
#define Q_DIM 8192
#define H_DIM 230
#define K2    256              // bf16 K padded to multiple of 32
#define SQ    (S_DIM * Q_DIM)
#define QB    16               // q-tile per block
#define NBLK  (Q_DIM / QB)     // 512 main blocks

using short8 = __attribute__((ext_vector_type(8))) short;   // 8 bf16 (4 VGPRs)
using f32x4  = __attribute__((ext_vector_type(4))) float;

__device__ __forceinline__ float bf16_to_f32(short bits) {
    unsigned u = ((unsigned)(unsigned short)bits) << 16;
    return __uint_as_float(u);
}

// ---------------- Kernel 1: prep ----------------
// grid=128, block=256(==K2). xwb[s][k]=bf16(w*x), zero-padded; asum[s]=sum w*x^2.
__global__ __launch_bounds__(256) void prep_kernel(
    const float* __restrict__ x, const float* __restrict__ w,
    __hip_bfloat16* __restrict__ xwb, float* __restrict__ asum)
{
    __shared__ float lred[4];
    const int tid = threadIdx.x, s = blockIdx.x;
    float xv = 0.f, wv = 0.f;
    if (tid < H_DIM) { xv = x[s * H_DIM + tid]; wv = w[tid]; }
    float wx = wv * xv;
    xwb[s * K2 + tid] = __float2bfloat16(wx);   // 0 for tid>=230

    float p = wx * xv;                          // w*x^2
    #pragma unroll
    for (int off = 32; off >= 1; off >>= 1) p += __shfl_down(p, off, 64);
    if ((tid & 63) == 0) lred[tid >> 6] = p;
    __syncthreads();
    if (tid == 0) asum[s] = lred[0] + lred[1] + lred[2] + lred[3];
}

// ---------------- Kernel 2: main (MFMA GEMM + sigmoid + BCE) ----------------
// grid=512, block=256 (4 waves). Block: all 128 s x 16 q. Wave w: s in [32w,32w+32).
__global__ __launch_bounds__(256) void main_kernel(
    const float* __restrict__ y, const int* __restrict__ label,
    const __hip_bfloat16* __restrict__ xwb, const float* __restrict__ asum,
    const float* __restrict__ w, const float* __restrict__ bptr,
    float* __restrict__ out, float* __restrict__ lossws)
{
    __shared__ __align__(16) short ylb[QB * K2];   // 8 KB bf16, XOR-swizzled
    __shared__ float cpart[16][17];
    __shared__ float cq[QB];
    __shared__ float asl[S_DIM];
    __shared__ float lred[4];

    const int tid = threadIdx.x;
    const int q0 = blockIdx.x * QB;
    const int wid = tid >> 6, l = tid & 63;
    const int lm = l & 15, lh = l >> 4;
    const int qg = q0 + lm;
    char* ylc = reinterpret_cast<char*>(ylb);

    if (tid < S_DIM) asl[tid] = asum[tid];

    // ---- stage y tile (16 rows x 230 f32) -> bf16 swizzled LDS ----
    // Tile is one contiguous span: q0*230 f32, 16B-aligned (q0*920 % 16 == 0).
    const float4* ysrc4 = reinterpret_cast<const float4*>(y + (size_t)q0 * H_DIM);
    #pragma unroll
    for (int it = 0; it < 4; ++it) {
        int i4 = tid + 256 * it;
        if (i4 < (QB * H_DIM) / 4) {
            float4 v = ysrc4[i4];
            float vv[4] = {v.x, v.y, v.z, v.w};
            #pragma unroll
            for (int j = 0; j < 4; ++j) {
                int ee = i4 * 4 + j;
                int r = ee / H_DIM;            // const divide -> magic mul
                int c = ee - r * H_DIM;
                int byt = ((r << 9) + (c << 1)) ^ ((r & 7) << 4);
                *reinterpret_cast<__hip_bfloat16*>(ylc + byt) = __float2bfloat16(vv[j]);
            }
        }
    }
    {   // zero-fill k = 230..255
        const int r = tid & 15;
        for (int c = H_DIM + (tid >> 4); c < K2; c += 16) {
            int byt = ((r << 9) + (c << 1)) ^ ((r & 7) << 4);
            *reinterpret_cast<__hip_bfloat16*>(ylc + byt) = __float2bfloat16(0.0f);
        }
    }

    // ---- label prefetch: issue AFTER staging reads, consume in epilogue ----
    // Rows s = wid*32 + f*16 + lh*4 + r, col qg. In flight across the barriers
    // and the MFMA loop (vmcnt-counted; compiler waits before epilogue use).
    int labs[2][4];
    #pragma unroll
    for (int f = 0; f < 2; ++f)
        #pragma unroll
        for (int r = 0; r < 4; ++r)
            labs[f][r] = label[(size_t)(wid * 32 + f * 16 + lh * 4 + r) * Q_DIM + qg];

    __syncthreads();

    // ---- c[q] = sum_k w[k]*y~[q,k]^2 from the bf16 tile (vector LDS reads) ----
    {
        const int r = tid & 15, ch = tid >> 4;     // ch in 0..15, 16 k each
        const int k0 = ch * 16;
        int byt0 = ((r << 9) + (k0 << 1)) ^ ((r & 7) << 4);
        int byt1 = ((r << 9) + ((k0 + 8) << 1)) ^ ((r & 7) << 4);
        short8 v8a = *reinterpret_cast<const short8*>(ylc + byt0);
        short8 v8b = *reinterpret_cast<const short8*>(ylc + byt1);
        float p = 0.f;
        #pragma unroll
        for (int j = 0; j < 8; ++j) {
            float va = bf16_to_f32(v8a[j]);
            float wa = (k0 + j < H_DIM) ? w[k0 + j] : 0.f;
            p = fmaf(wa * va, va, p);
        }
        #pragma unroll
        for (int j = 0; j < 8; ++j) {
            float vb = bf16_to_f32(v8b[j]);
            float wb = (k0 + 8 + j < H_DIM) ? w[k0 + 8 + j] : 0.f;
            p = fmaf(wb * vb, vb, p);
        }
        cpart[ch][r] = p;
    }
    __syncthreads();
    if (tid < QB) {
        float c = 0.f;
        #pragma unroll
        for (int ch = 0; ch < 16; ++ch) c += cpart[ch][tid];
        cq[tid] = c + bptr[0];                     // fold bias in
    }
    __syncthreads();

    // ---- MFMA k-loop: wave computes 32 s x 16 q ----
    f32x4 acc0 = {0.f, 0.f, 0.f, 0.f};
    f32x4 acc1 = {0.f, 0.f, 0.f, 0.f};
    const short* xwp = reinterpret_cast<const short*>(xwb);
    const int arow0 = (wid * 32 + lm) * K2;        // A rows [32w, 32w+16)
    const int arow1 = arow0 + 16 * K2;             // A rows [32w+16, 32w+32)
    #pragma unroll
    for (int ks = 0; ks < K2 / 32; ++ks) {
        const int kof = ks * 32 + lh * 8;
        short8 a0 = *reinterpret_cast<const short8*>(xwp + arow0 + kof);
        short8 a1 = *reinterpret_cast<const short8*>(xwp + arow1 + kof);
        int byt = ((lm << 9) + (kof << 1)) ^ ((lm & 7) << 4);
        short8 bf = *reinterpret_cast<const short8*>(ylc + byt);
        acc0 = __builtin_amdgcn_mfma_f32_16x16x32_bf16(a0, bf, acc0, 0, 0, 0);
        acc1 = __builtin_amdgcn_mfma_f32_16x16x32_bf16(a1, bf, acc1, 0, 0, 0);
    }

    // ---- epilogue: z = a[s]+c[q]+b-2*dot ; sigmoid -> out ; BCE partial ----
    float lsum = 0.f;
    #pragma unroll
    for (int f = 0; f < 2; ++f) {
        f32x4 ac = f ? acc1 : acc0;
        #pragma unroll
        for (int r = 0; r < 4; ++r) {
            int s = wid * 32 + f * 16 + lh * 4 + r;   // D row=(l>>4)*4+r, col=l&15
            float z = asl[s] + cq[lm] - 2.0f * ac[r];
            float sc = 1.0f / (1.0f + __expf(-z));
            size_t o = (size_t)s * Q_DIM + qg;
            out[o] = sc;
            float lab = (float)labs[f][r];
            float bce = fmaxf(z, 0.f) - z * lab + log1pf(__expf(-fabsf(z)));
            lsum += bce;
        }
    }
    #pragma unroll
    for (int off = 32; off >= 1; off >>= 1) lsum += __shfl_down(lsum, off, 64);
    if (l == 0) lred[wid] = lsum;
    __syncthreads();
    if (tid == 0)
        lossws[blockIdx.x] = lred[0] + lred[1] + lred[2] + lred[3];
}

// ---------------- Kernel 3: deterministic loss reduce ----------------
__global__ __launch_bounds__(256) void loss_reduce_kernel(
    const float* __restrict__ lossws, float* __restrict__ out)
{
    __shared__ float lred[4];
    const int tid = threadIdx.x;
    float p = lossws[tid] + lossws[tid + 256];     // NBLK=512 partials
    #pragma unroll
    for (int off = 32; off >= 1; off >>= 1) p += __shfl_down(p, off, 64);
    if ((tid & 63) == 0) lred[tid >> 6] = p;
    __syncthreads();
    if (tid == 0)
        out[SQ] = (lred[0] + lred[1] + lred[2] + lred[3]) * (1.0f / (float)SQ);
}

extern "C" void kernel_launch(void* const* d_in, const int* in_sizes, int n_in,
                              void* d_out, int out_size, void* d_ws, size_t ws_size,
                              hipStream_t stream) {
    const float* x = (const float*)d_in[0];     // [128,230]
    const float* y = (const float*)d_in[1];     // [8192,230]
    const int* label = (const int*)d_in[2];     // [128,8192]
    const float* w = (const float*)d_in[3];     // [230]
    const float* b = (const float*)d_in[4];     // [1]
    float* out = (float*)d_out;                 // [128*8192 + 1]

    __hip_bfloat16* xwb = (__hip_bfloat16*)d_ws;            // [128][256] bf16 = 64 KB
    float* asum = (float*)((char*)d_ws + S_DIM * K2 * 2);   // [128]
    float* lossws = asum + S_DIM;                           // [512]

    prep_kernel<<<S_DIM, 256, 0, stream>>>(x, w, xwb, asum);
    main_kernel<<<NBLK, 256, 0, stream>>>(y, label, xwb, asum, w, b, out, lossws);
    loss_reduce_kernel<<<1, 256, 0, stream>>>(lossws, out);
}

// Round 9
// 20.398 us; speedup vs baseline: 1.6689x; 1.0757x over previous
//
#include <hip/hip_runtime.h>
#include <hip/hip_bf16.h>

// S=128, Q=8192, H=230
//   logits[s,q] = a[s] + c[q] + b - 2*sum_k wx[s,k]*y[q,k]
//   a[s]=sum w*x^2 (f32), c[q]=sum w*y^2 (f32), dot via bf16 MFMA (f32 acc).
// r8-winner structure (21.9us) with ONE delta: main block=512 (8 waves,
// one 16x16 tile per wave) -> 4 waves/SIMD for latency hiding.
// All reductions fixed-order (graph replay must be bitwise identical).

#define S_DIM 128
#define Q_DIM 8192
#define H_DIM 230
#define K2    256              // bf16 K padded to multiple of 32
#define SQ    (S_DIM * Q_DIM)
#define QB    16               // q-tile per block
#define NBLK  (Q_DIM / QB)     // 512 main blocks

using short8 = __attribute__((ext_vector_type(8))) short;   // 8 bf16 (4 VGPRs)
using f32x4  = __attribute__((ext_vector_type(4))) float;

__device__ __forceinline__ float bf16_to_f32(short bits) {
    unsigned u = ((unsigned)(unsigned short)bits) << 16;
    return __uint_as_float(u);
}

// ---------------- Kernel 1: prep ----------------
// grid=128, block=256(==K2). xwb[s][k]=bf16(w*x), zero-padded; asum[s]=sum w*x^2.
__global__ __launch_bounds__(256) void prep_kernel(
    const float* __restrict__ x, const float* __restrict__ w,
    __hip_bfloat16* __restrict__ xwb, float* __restrict__ asum)
{
    __shared__ float lred[4];
    const int tid = threadIdx.x, s = blockIdx.x;
    float xv = 0.f, wv = 0.f;
    if (tid < H_DIM) { xv = x[s * H_DIM + tid]; wv = w[tid]; }
    float wx = wv * xv;
    xwb[s * K2 + tid] = __float2bfloat16(wx);   // 0 for tid>=230

    float p = wx * xv;                          // w*x^2
    #pragma unroll
    for (int off = 32; off >= 1; off >>= 1) p += __shfl_down(p, off, 64);
    if ((tid & 63) == 0) lred[tid >> 6] = p;
    __syncthreads();
    if (tid == 0) asum[s] = lred[0] + lred[1] + lred[2] + lred[3];
}

// ---------------- Kernel 2: main (MFMA GEMM + sigmoid + BCE) ----------------
// grid=512, block=512 (8 waves). Block: all 128 s x 16 q.
// Wave wid: s in [16*wid, 16*wid+16), one 16x16 MFMA tile (single acc).
__global__ __launch_bounds__(512, 4) void main_kernel(
    const float* __restrict__ y, const int* __restrict__ label,
    const __hip_bfloat16* __restrict__ xwb, const float* __restrict__ asum,
    const float* __restrict__ w, const float* __restrict__ bptr,
    float* __restrict__ out, float* __restrict__ lossws)
{
    __shared__ __align__(16) short ylb[QB * K2];   // 8 KB bf16, XOR-swizzled
    __shared__ float cpart[32][17];
    __shared__ float cq[QB];
    __shared__ float asl[S_DIM];
    __shared__ float lred[8];

    const int tid = threadIdx.x;
    const int q0 = blockIdx.x * QB;
    const int wid = tid >> 6, l = tid & 63;
    const int lm = l & 15, lh = l >> 4;
    const int s_base = wid * 16;
    const int qg = q0 + lm;
    char* ylc = reinterpret_cast<char*>(ylb);

    if (tid < S_DIM) asl[tid] = asum[tid];

    // ---- stage y tile (16 rows x 230 f32) -> bf16 swizzled LDS ----
    // Tile is one contiguous span: q0*230 f32, 16B-aligned (q0*920 % 16 == 0).
    const float4* ysrc4 = reinterpret_cast<const float4*>(y + (size_t)q0 * H_DIM);
    #pragma unroll
    for (int it = 0; it < 2; ++it) {
        int i4 = tid + 512 * it;
        if (i4 < (QB * H_DIM) / 4) {
            float4 v = ysrc4[i4];
            float vv[4] = {v.x, v.y, v.z, v.w};
            #pragma unroll
            for (int j = 0; j < 4; ++j) {
                int ee = i4 * 4 + j;
                int r = ee / H_DIM;            // const divide -> magic mul
                int c = ee - r * H_DIM;
                int byt = ((r << 9) + (c << 1)) ^ ((r & 7) << 4);
                *reinterpret_cast<__hip_bfloat16*>(ylc + byt) = __float2bfloat16(vv[j]);
            }
        }
    }
    if (tid < QB * (K2 - H_DIM)) {   // zero-fill k = 230..255 (16*26 = 416)
        int r = tid & 15, c = H_DIM + (tid >> 4);
        int byt = ((r << 9) + (c << 1)) ^ ((r & 7) << 4);
        *reinterpret_cast<__hip_bfloat16*>(ylc + byt) = __float2bfloat16(0.0f);
    }

    // ---- label prefetch: issue AFTER staging reads, consume in epilogue ----
    // Rows s = s_base + lh*4 + r, col qg. In flight across barriers + MFMA.
    int labs[4];
    #pragma unroll
    for (int r = 0; r < 4; ++r)
        labs[r] = label[(size_t)(s_base + lh * 4 + r) * Q_DIM + qg];

    __syncthreads();

    // ---- c[q] = sum_k w[k]*y~[q,k]^2 (32 chunks of 8 k, vector LDS reads) ----
    {
        const int r = tid & 15, ch = tid >> 4;     // ch in 0..31
        const int k0 = ch * 8;
        int byt = ((r << 9) + (k0 << 1)) ^ ((r & 7) << 4);
        short8 v8 = *reinterpret_cast<const short8*>(ylc + byt);
        float p = 0.f;
        #pragma unroll
        for (int j = 0; j < 8; ++j) {
            float v = bf16_to_f32(v8[j]);
            float wk = (k0 + j < H_DIM) ? w[k0 + j] : 0.f;
            p = fmaf(wk * v, v, p);
        }
        cpart[ch][r] = p;
    }
    __syncthreads();
    if (tid < QB) {
        float c = 0.f;
        #pragma unroll
        for (int ch = 0; ch < 32; ++ch) c += cpart[ch][tid];
        cq[tid] = c + bptr[0];                     // fold bias in
    }
    __syncthreads();

    // ---- MFMA k-loop: wave computes 16 s x 16 q (single acc) ----
    f32x4 acc = {0.f, 0.f, 0.f, 0.f};
    const short* A = reinterpret_cast<const short*>(xwb) + (s_base + lm) * K2 + lh * 8;
    #pragma unroll
    for (int ks = 0; ks < K2 / 32; ++ks) {
        const int kof = ks * 32 + lh * 8;
        short8 a = *reinterpret_cast<const short8*>(A + ks * 32);
        int byt = ((lm << 9) + (kof << 1)) ^ ((lm & 7) << 4);
        short8 bf = *reinterpret_cast<const short8*>(ylc + byt);
        acc = __builtin_amdgcn_mfma_f32_16x16x32_bf16(a, bf, acc, 0, 0, 0);
    }

    // ---- epilogue: z = a[s]+c[q]+b-2*dot ; sigmoid -> out ; BCE partial ----
    float lsum = 0.f;
    const float cqv = cq[lm];
    #pragma unroll
    for (int r = 0; r < 4; ++r) {
        int s = s_base + lh * 4 + r;               // D row=(l>>4)*4+r, col=l&15
        float z = asl[s] + cqv - 2.0f * acc[r];
        float sc = 1.0f / (1.0f + __expf(-z));
        size_t o = (size_t)s * Q_DIM + qg;
        out[o] = sc;
        float lab = (float)labs[r];
        float bce = fmaxf(z, 0.f) - z * lab + log1pf(__expf(-fabsf(z)));
        lsum += bce;
    }
    #pragma unroll
    for (int off = 32; off >= 1; off >>= 1) lsum += __shfl_down(lsum, off, 64);
    if (l == 0) lred[wid] = lsum;
    __syncthreads();
    if (tid == 0) {
        float blk = 0.f;
        #pragma unroll
        for (int i = 0; i < 8; ++i) blk += lred[i];
        lossws[blockIdx.x] = blk;
    }
}

// ---------------- Kernel 3: deterministic loss reduce ----------------
__global__ __launch_bounds__(256) void loss_reduce_kernel(
    const float* __restrict__ lossws, float* __restrict__ out)
{
    __shared__ float lred[4];
    const int tid = threadIdx.x;
    float p = lossws[tid] + lossws[tid + 256];     // NBLK=512 partials
    #pragma unroll
    for (int off = 32; off >= 1; off >>= 1) p += __shfl_down(p, off, 64);
    if ((tid & 63) == 0) lred[tid >> 6] = p;
    __syncthreads();
    if (tid == 0)
        out[SQ] = (lred[0] + lred[1] + lred[2] + lred[3]) * (1.0f / (float)SQ);
}

extern "C" void kernel_launch(void* const* d_in, const int* in_sizes, int n_in,
                              void* d_out, int out_size, void* d_ws, size_t ws_size,
                              hipStream_t stream) {
    const float* x = (const float*)d_in[0];     // [128,230]
    const float* y = (const float*)d_in[1];     // [8192,230]
    const int* label = (const int*)d_in[2];     // [128,8192]
    const float* w = (const float*)d_in[3];     // [230]
    const float* b = (const float*)d_in[4];     // [1]
    float* out = (float*)d_out;                 // [128*8192 + 1]

    __hip_bfloat16* xwb = (__hip_bfloat16*)d_ws;            // [128][256] bf16 = 64 KB
    float* asum = (float*)((char*)d_ws + S_DIM * K2 * 2);   // [128]
    float* lossws = asum + S_DIM;                           // [512]

    prep_kernel<<<S_DIM, 256, 0, stream>>>(x, w, xwb, asum);
    main_kernel<<<NBLK, 512, 0, stream>>>(y, label, xwb, asum, w, b, out, lossws);
    loss_reduce_kernel<<<1, 256, 0, stream>>>(lossws, out);
}